// Round 9
// baseline (328.767 us; speedup 1.0000x reference)
//
#include <hip/hip_runtime.h>
#include <hip/hip_fp16.h>

// NNConv on MI355X. msg[E x 32] = Z[E x 4096] @ w2r[4096 x 32],
// Z[e, c*32+i] = h[e,c]*xs[e,i] built on the fly in fp16 A-fragments via
// v_pk_mul_f16. 4 waves x 64 edges, async-dbuf 4-c w2 chunks (1 barrier/chunk,
// global_load_lds width=16), split-slice hT (8 KB), LDS 24.25 KB.
// Round 9: persistent eaf restored (kills 4x ea re-fetch, R8's +140 MB HBM)
// + __launch_bounds__(256,6): 6 blocks/CU (VGPR ~70 < 85 cap, R8 measured 48).

#define NN 25000
#define EE 400000

typedef _Float16 f16x8 __attribute__((ext_vector_type(8)));
typedef float    f32x16 __attribute__((ext_vector_type(16)));

__device__ __forceinline__ void async16(const void* g, void* l) {
    // one 16B element per lane; LDS dest = wave-uniform base + lane*16
    __builtin_amdgcn_global_load_lds(
        (const __attribute__((address_space(1))) unsigned int*)g,
        (__attribute__((address_space(3))) unsigned int*)l, 16, 0, 0);
}

// ---------------- prep: pack w1/w2/b2 to fp16 fragment layout + zero replicas ----------------
__global__ __launch_bounds__(256) void prep_kernel(
    const float* __restrict__ w1, const float* __restrict__ w2,
    const float* __restrict__ b2,
    _Float16* __restrict__ w2p, _Float16* __restrict__ w1p, _Float16* __restrict__ b2p,
    float4* __restrict__ part4, int nzero4)
{
    int b = blockIdx.x;
    if (b < 532) {                       // 532*256 = 136192 pack threads, exact
        int t = b * 256 + threadIdx.x;
        if (t < 131072) {
            int j = t & 7, lane = (t >> 3) & 63, ih = (t >> 9) & 1, c = t >> 10;
            w2p[t] = (_Float16)w2[c * 1024 + (ih * 16 + ((lane >> 5) << 3) + j) * 32 + (lane & 31)];
        } else if (t < 135168) {
            int u = t - 131072;
            int j = u & 7, lane = (u >> 3) & 63, kk = (u >> 9) & 1, r = u >> 10;
            w1p[u] = (_Float16)w1[(kk * 16 + ((lane >> 5) << 3) + j) * 128 + r * 32 + (lane & 31)];
        } else {
            int u = t - 135168;
            int j = u & 7, lane = (u >> 3) & 63, ih = u >> 9;
            b2p[u] = (_Float16)b2[(ih * 16 + ((lane >> 5) << 3) + j) * 32 + (lane & 31)];
        }
    } else {
        int z = (b - 532) * 256 + threadIdx.x;
        if (z < nzero4) part4[z] = make_float4(0.f, 0.f, 0.f, 0.f);
    }
}

// ---------------- final: out = x@root + bias + sum(replicas) ----------------
__global__ __launch_bounds__(256) void final_kernel(
    const float* __restrict__ x, const float* __restrict__ root,
    const float* __restrict__ bias, const float* __restrict__ part,
    int ncopies, float* __restrict__ out)
{
    int gid = blockIdx.x * 256 + threadIdx.x;   // exactly NN*32
    int n = gid >> 5, o = gid & 31;
    float acc = bias[o];
    const float* xr = x + (n << 5);
#pragma unroll
    for (int i = 0; i < 32; ++i)
        acc = fmaf(xr[i], root[(i << 5) + o], acc);
    for (int c = 0; c < ncopies; ++c) acc += part[(size_t)c * 800000 + gid];
    out[gid] = acc;
}

// ---------------- fused MFMA edge kernel ----------------
// 256 thr = 4 waves x 64 edges (2 groups of 32) = 256 edges/block, 1563 blocks.
__global__ __launch_bounds__(256, 6) void edge_kernel(
    const float*    __restrict__ x,
    const int*      __restrict__ ei,
    const float*    __restrict__ ea,
    const float*    __restrict__ b1,
    const _Float16* __restrict__ w2p,
    const _Float16* __restrict__ w1p,
    const _Float16* __restrict__ b2p,
    float* __restrict__ outp, int copyMask)
{
    __shared__ __align__(16) _Float16 w2c[2][4096];        // 2 x 8 KB (4-c chunks)
    __shared__ unsigned short hTq[4][16][32][2];           // 8 KB: 16-slot split hT

    const int t    = threadIdx.x;
    const int w    = t >> 6;
    const int lane = t & 63;
    const int l    = lane & 31;
    const int half = lane >> 5;

    const int  ebraw = blockIdx.x * 256 + w * 64;
    const bool live  = (ebraw + 64) <= EE;                 // wave-uniform
    const int  ebw   = live ? ebraw : (EE - 64);

    float* __restrict__ myout = outp + (size_t)(blockIdx.x & copyMask) * 800000;

    union u8h { f16x8 v; __half2 h2[4]; };

    // ---- async w2 chunk staging: 2 x global_load_lds(16B) per wave per chunk ----
    const char* w2g = (const char*)w2p;
    auto issueChunk = [&](int cc, int buf) {
#pragma unroll
        for (int s = 0; s < 2; ++s) {
            const int slot = s * 256 + w * 64;               // wave-uniform
            async16(w2g + (size_t)cc * 8192 + (size_t)(slot + lane) * 16,
                    (void*)&w2c[buf][slot * 8]);
        }
    };
    issueChunk(0, 0);                      // get DMA flying before reg loads
    issueChunk(1, 1);

    // ---- persistent edge-attr fragments (fp16), 2 groups ----
    u8h eaf[2][2];
#pragma unroll
    for (int g = 0; g < 2; ++g)
#pragma unroll
        for (int kk = 0; kk < 2; ++kk) {
            const float* p = ea + (ebw + g * 32 + l) * 32 + kk * 16 + half * 8;
            float4 a0 = *(const float4*)p;
            float4 a1 = *(const float4*)(p + 4);
            eaf[g][kk].h2[0] = __float22half2_rn(make_float2(a0.x, a0.y));
            eaf[g][kk].h2[1] = __float22half2_rn(make_float2(a0.z, a0.w));
            eaf[g][kk].h2[2] = __float22half2_rn(make_float2(a1.x, a1.y));
            eaf[g][kk].h2[3] = __float22half2_rn(make_float2(a1.z, a1.w));
        }

    // ---- gather xs rows (fp16 pairs) for 2 groups ----
    __half2 xs0[8], xs1[8];
    {
        int s0 = ei[ebw + l], s1 = ei[ebw + 32 + l];
#pragma unroll
        for (int ih = 0; ih < 2; ++ih) {
            float4 a0 = *(const float4*)(x + s0 * 32 + ih * 16 + half * 8);
            float4 a1 = *(const float4*)(x + s0 * 32 + ih * 16 + half * 8 + 4);
            xs0[ih*4+0] = __float22half2_rn(make_float2(a0.x, a0.y));
            xs0[ih*4+1] = __float22half2_rn(make_float2(a0.z, a0.w));
            xs0[ih*4+2] = __float22half2_rn(make_float2(a1.x, a1.y));
            xs0[ih*4+3] = __float22half2_rn(make_float2(a1.z, a1.w));
            float4 c0 = *(const float4*)(x + s1 * 32 + ih * 16 + half * 8);
            float4 c1 = *(const float4*)(x + s1 * 32 + ih * 16 + half * 8 + 4);
            xs1[ih*4+0] = __float22half2_rn(make_float2(c0.x, c0.y));
            xs1[ih*4+1] = __float22half2_rn(make_float2(c0.z, c0.w));
            xs1[ih*4+2] = __float22half2_rn(make_float2(c1.x, c1.y));
            xs1[ih*4+3] = __float22half2_rn(make_float2(c1.z, c1.w));
        }
    }

    f32x16 acc0, acc1;
#pragma unroll
    for (int i = 0; i < 16; ++i) { acc0[i] = 0.f; acc1[i] = 0.f; }

    unsigned held[8];                        // rows 16-31 of current slice, (g0,g1) packed

    // ---- phase-1 slice for r: rows 0-15 -> hTq slots now, rows 16-31 -> held ----
    auto phase1 = [&](int r) {
        f16x8 w1f0 = *(const f16x8*)(w1p + ((r * 2 + 0) * 64 + lane) * 8);
        f16x8 w1f1 = *(const f16x8*)(w1p + ((r * 2 + 1) * 64 + lane) * 8);
#pragma unroll
        for (int g = 0; g < 2; ++g) {
            f32x16 h;
#pragma unroll
            for (int i = 0; i < 16; ++i) h[i] = 0.f;
            h = __builtin_amdgcn_mfma_f32_32x32x16_f16(w1f0, eaf[g][0].v, h, 0, 0, 0);
            h = __builtin_amdgcn_mfma_f32_32x32x16_f16(w1f1, eaf[g][1].v, h, 0, 0, 0);
#pragma unroll
            for (int i = 0; i < 16; ++i) {
                int row = (i & 3) + ((i >> 2) << 3) + (half << 2);   // verified C/D map
                float hv = fmaxf(h[i] + b1[r * 32 + row], 0.f);
                unsigned short us = __half_as_ushort(__float2half(hv));
                if (i < 8) {
                    hTq[w][row][l][g] = us;                  // rows 0-15: slot == row
                } else {
                    int j = i - 8;                           // rows 16-31: hold in regs
                    if (g == 0) held[j] = us;
                    else        held[j] |= (unsigned)us << 16;
                }
            }
        }
    };

    // writes held rows into slots (wave-private; between chunk q=3 and q=4)
    auto flushHeld = [&]() {
#pragma unroll
        for (int j = 0; j < 8; ++j) {
            int slot = (j & 3) + ((j >> 2) << 3) + (half << 2);   // row-16
            *(unsigned*)&hTq[w][slot][l][0] = held[j];
        }
    };

    // compute one 4-c chunk from RB
    auto compute = [&](int cc, const _Float16* RB) {
#pragma unroll
        for (int cl = 0; cl < 4; ++cl) {
            unsigned u = *(const unsigned*)&hTq[w][((cc & 3) << 2) + cl][l][0];
            __half2 hp = *reinterpret_cast<const __half2*>(&u);
            __half2 h0 = __half2half2(__low2half(hp));       // dup for group 0
            __half2 h1 = __half2half2(__high2half(hp));      // dup for group 1
#pragma unroll
            for (int ih = 0; ih < 2; ++ih) {
                f16x8 bfr = *(const f16x8*)(RB + (((cl << 1) + ih) * 64 + lane) * 8);
                u8h A;
#pragma unroll
                for (int p = 0; p < 4; ++p)
                    A.h2[p] = __hmul2(h0, xs0[ih * 4 + p]);      // v_pk_mul_f16
                acc0 = __builtin_amdgcn_mfma_f32_32x32x16_f16(A.v, bfr, acc0, 0, 0, 0);
#pragma unroll
                for (int p = 0; p < 4; ++p)
                    A.h2[p] = __hmul2(h1, xs1[ih * 4 + p]);
                acc1 = __builtin_amdgcn_mfma_f32_32x32x16_f16(A.v, bfr, acc1, 0, 0, 0);
            }
        }
    };

    // ---- pipeline: c0/c1 already in flight; then 1 barrier per chunk ----
    phase1(0);
    __syncthreads();                       // drains both prologue loads

#pragma unroll 1
    for (int r = 0; r < 4; ++r) {
        if (r > 0) phase1(r);              // wave-private hTq: no barrier needed
#pragma unroll
        for (int q = 0; q < 8; ++q) {
            const int cc = r * 8 + q;
            if (q == 4) flushHeld();       // rows 16-31 into the 16 slots
            compute(cc, w2c[q & 1]);
            __syncthreads();               // all waves done reading buf (q&1)
            if (cc + 2 < 32) issueChunk(cc + 2, q & 1);   // async refill; drains
        }                                  // at the barrier one chunk later
    }

    // ---- b2 contribution: extra K-step with h == 1 (A-fragment = xs, no VALU) ----
#pragma unroll
    for (int ih = 0; ih < 2; ++ih) {
        f16x8 bfr = *(const f16x8*)(b2p + (ih * 64 + lane) * 8);
        u8h A;
#pragma unroll
        for (int p = 0; p < 4; ++p) A.h2[p] = xs0[ih * 4 + p];
        acc0 = __builtin_amdgcn_mfma_f32_32x32x16_f16(A.v, bfr, acc0, 0, 0, 0);
#pragma unroll
        for (int p = 0; p < 4; ++p) A.h2[p] = xs1[ih * 4 + p];
        acc1 = __builtin_amdgcn_mfma_f32_32x32x16_f16(A.v, bfr, acc1, 0, 0, 0);
    }

    // ---- scatter into this block's replica (skip for clamped tail waves) ----
    if (live) {
#pragma unroll
        for (int i = 0; i < 16; ++i) {
            int el = (i & 3) + ((i >> 2) << 3) + (half << 2);
            atomicAdd(myout + ei[EE + ebw +      el] * 32 + l, acc0[i]);
            atomicAdd(myout + ei[EE + ebw + 32 + el] * 32 + l, acc1[i]);
        }
    }
}

extern "C" void kernel_launch(void* const* d_in, const int* in_sizes, int n_in,
                              void* d_out, int out_size, void* d_ws, size_t ws_size,
                              hipStream_t stream) {
    const float* x    = (const float*)d_in[0];
    const int*   ei   = (const int*)  d_in[1];
    const float* ea   = (const float*)d_in[2];
    const float* w1   = (const float*)d_in[3];
    const float* b1   = (const float*)d_in[4];
    const float* w2   = (const float*)d_in[5];
    const float* b2   = (const float*)d_in[6];
    const float* root = (const float*)d_in[7];
    const float* bias = (const float*)d_in[8];
    float* out = (float*)d_out;

    _Float16* w2p = (_Float16*)d_ws;                      // 262144 B
    _Float16* w1p = (_Float16*)((char*)d_ws + 262144);    //   8192 B
    _Float16* b2p = (_Float16*)((char*)d_ws + 270336);    //   2048 B
    const size_t partOff = 272384;
    const size_t one = 800000ull * sizeof(float);         // 3.2 MB per replica
    size_t avail = (ws_size > partOff) ? ws_size - partOff : 0;
    int nc = 0;
    for (int c = 8; c >= 1; c >>= 1)
        if ((size_t)c * one <= avail) { nc = c; break; }

    float* part = (float*)((char*)d_ws + partOff);
    if (nc > 0) {
        int nzero4 = nc * 200000;                         // float4 count
        int zb = (nzero4 + 255) / 256;
        prep_kernel<<<532 + zb, 256, 0, stream>>>(w1, w2, b2, w2p, w1p, b2p,
                                                  (float4*)part, nzero4);
        edge_kernel<<<(EE + 255) / 256, 256, 0, stream>>>(x, ei, ea, b1, w2p, w1p, b2p,
                                                          part, nc - 1);
        final_kernel<<<(NN * 32) / 256, 256, 0, stream>>>(x, root, bias, part, nc, out);
    } else {
        prep_kernel<<<532, 256, 0, stream>>>(w1, w2, b2, w2p, w1p, b2p, (float4*)part, 0);
        final_kernel<<<(NN * 32) / 256, 256, 0, stream>>>(x, root, bias, part, 0, out);
        edge_kernel<<<(EE + 255) / 256, 256, 0, stream>>>(x, ei, ea, b1, w2p, w1p, b2p,
                                                          out, 0);
    }
}

// Round 10
// 256.816 us; speedup vs baseline: 1.2802x; 1.2802x over previous
//
#include <hip/hip_runtime.h>
#include <hip/hip_fp16.h>

// NNConv on MI355X. msg[E x 32] = Z[E x 4096] @ w2r[4096 x 32],
// Z[e, c*32+i] = h[e,c]*xs[e,i] built on the fly in fp16 A-fragments via
// v_pk_mul_f16. 4 waves x 64 edges, async-dbuf 4-c w2 chunks (1 barrier/chunk,
// global_load_lds width=16), split-slice hT (8 KB), LDS 24.25 KB.
// Round 10: R8 + persistent eaf (ea read ONCE; phase-1 A-fragments are
// r-independent) at __launch_bounds__(256,5) -- R7/R9 proved 6 blocks/CU
// spills (cap 85 < ~90 needed); 5-wave cap 102 fits R8's 48 + 16 eaf.

#define NN 25000
#define EE 400000

typedef _Float16 f16x8 __attribute__((ext_vector_type(8)));
typedef float    f32x16 __attribute__((ext_vector_type(16)));

__device__ __forceinline__ void async16(const void* g, void* l) {
    // one 16B element per lane; LDS dest = wave-uniform base + lane*16
    __builtin_amdgcn_global_load_lds(
        (const __attribute__((address_space(1))) unsigned int*)g,
        (__attribute__((address_space(3))) unsigned int*)l, 16, 0, 0);
}

// ---------------- prep: pack w1/w2/b2 to fp16 fragment layout + zero replicas ----------------
__global__ __launch_bounds__(256) void prep_kernel(
    const float* __restrict__ w1, const float* __restrict__ w2,
    const float* __restrict__ b2,
    _Float16* __restrict__ w2p, _Float16* __restrict__ w1p, _Float16* __restrict__ b2p,
    float4* __restrict__ part4, int nzero4)
{
    int b = blockIdx.x;
    if (b < 532) {                       // 532*256 = 136192 pack threads, exact
        int t = b * 256 + threadIdx.x;
        if (t < 131072) {
            int j = t & 7, lane = (t >> 3) & 63, ih = (t >> 9) & 1, c = t >> 10;
            w2p[t] = (_Float16)w2[c * 1024 + (ih * 16 + ((lane >> 5) << 3) + j) * 32 + (lane & 31)];
        } else if (t < 135168) {
            int u = t - 131072;
            int j = u & 7, lane = (u >> 3) & 63, kk = (u >> 9) & 1, r = u >> 10;
            w1p[u] = (_Float16)w1[(kk * 16 + ((lane >> 5) << 3) + j) * 128 + r * 32 + (lane & 31)];
        } else {
            int u = t - 135168;
            int j = u & 7, lane = (u >> 3) & 63, ih = u >> 9;
            b2p[u] = (_Float16)b2[(ih * 16 + ((lane >> 5) << 3) + j) * 32 + (lane & 31)];
        }
    } else {
        int z = (b - 532) * 256 + threadIdx.x;
        if (z < nzero4) part4[z] = make_float4(0.f, 0.f, 0.f, 0.f);
    }
}

// ---------------- final: out = x@root + bias + sum(replicas) ----------------
__global__ __launch_bounds__(256) void final_kernel(
    const float* __restrict__ x, const float* __restrict__ root,
    const float* __restrict__ bias, const float* __restrict__ part,
    int ncopies, float* __restrict__ out)
{
    int gid = blockIdx.x * 256 + threadIdx.x;   // exactly NN*32
    int n = gid >> 5, o = gid & 31;
    float acc = bias[o];
    const float* xr = x + (n << 5);
#pragma unroll
    for (int i = 0; i < 32; ++i)
        acc = fmaf(xr[i], root[(i << 5) + o], acc);
    for (int c = 0; c < ncopies; ++c) acc += part[(size_t)c * 800000 + gid];
    out[gid] = acc;
}

// ---------------- fused MFMA edge kernel ----------------
// 256 thr = 4 waves x 64 edges (2 groups of 32) = 256 edges/block, 1563 blocks.
__global__ __launch_bounds__(256, 5) void edge_kernel(
    const float*    __restrict__ x,
    const int*      __restrict__ ei,
    const float*    __restrict__ ea,
    const float*    __restrict__ b1,
    const _Float16* __restrict__ w2p,
    const _Float16* __restrict__ w1p,
    const _Float16* __restrict__ b2p,
    float* __restrict__ outp, int copyMask)
{
    __shared__ __align__(16) _Float16 w2c[2][4096];        // 2 x 8 KB (4-c chunks)
    __shared__ unsigned short hTq[4][16][32][2];           // 8 KB: 16-slot split hT

    const int t    = threadIdx.x;
    const int w    = t >> 6;
    const int lane = t & 63;
    const int l    = lane & 31;
    const int half = lane >> 5;

    const int  ebraw = blockIdx.x * 256 + w * 64;
    const bool live  = (ebraw + 64) <= EE;                 // wave-uniform
    const int  ebw   = live ? ebraw : (EE - 64);

    float* __restrict__ myout = outp + (size_t)(blockIdx.x & copyMask) * 800000;

    union u8h { f16x8 v; __half2 h2[4]; };

    // ---- async w2 chunk staging: 2 x global_load_lds(16B) per wave per chunk ----
    const char* w2g = (const char*)w2p;
    auto issueChunk = [&](int cc, int buf) {
#pragma unroll
        for (int s = 0; s < 2; ++s) {
            const int slot = s * 256 + w * 64;               // wave-uniform
            async16(w2g + (size_t)cc * 8192 + (size_t)(slot + lane) * 16,
                    (void*)&w2c[buf][slot * 8]);
        }
    };
    issueChunk(0, 0);                      // get DMA flying before reg loads
    issueChunk(1, 1);

    // ---- persistent edge-attr fragments (fp16), 2 groups; read ONCE ----
    u8h eaf[2][2];
#pragma unroll
    for (int g = 0; g < 2; ++g)
#pragma unroll
        for (int kk = 0; kk < 2; ++kk) {
            const float* p = ea + (ebw + g * 32 + l) * 32 + kk * 16 + half * 8;
            float4 a0 = *(const float4*)p;
            float4 a1 = *(const float4*)(p + 4);
            eaf[g][kk].h2[0] = __float22half2_rn(make_float2(a0.x, a0.y));
            eaf[g][kk].h2[1] = __float22half2_rn(make_float2(a0.z, a0.w));
            eaf[g][kk].h2[2] = __float22half2_rn(make_float2(a1.x, a1.y));
            eaf[g][kk].h2[3] = __float22half2_rn(make_float2(a1.z, a1.w));
        }

    // ---- gather xs rows (fp16 pairs) for 2 groups ----
    __half2 xs0[8], xs1[8];
    {
        int s0 = ei[ebw + l], s1 = ei[ebw + 32 + l];
#pragma unroll
        for (int ih = 0; ih < 2; ++ih) {
            float4 a0 = *(const float4*)(x + s0 * 32 + ih * 16 + half * 8);
            float4 a1 = *(const float4*)(x + s0 * 32 + ih * 16 + half * 8 + 4);
            xs0[ih*4+0] = __float22half2_rn(make_float2(a0.x, a0.y));
            xs0[ih*4+1] = __float22half2_rn(make_float2(a0.z, a0.w));
            xs0[ih*4+2] = __float22half2_rn(make_float2(a1.x, a1.y));
            xs0[ih*4+3] = __float22half2_rn(make_float2(a1.z, a1.w));
            float4 c0 = *(const float4*)(x + s1 * 32 + ih * 16 + half * 8);
            float4 c1 = *(const float4*)(x + s1 * 32 + ih * 16 + half * 8 + 4);
            xs1[ih*4+0] = __float22half2_rn(make_float2(c0.x, c0.y));
            xs1[ih*4+1] = __float22half2_rn(make_float2(c0.z, c0.w));
            xs1[ih*4+2] = __float22half2_rn(make_float2(c1.x, c1.y));
            xs1[ih*4+3] = __float22half2_rn(make_float2(c1.z, c1.w));
        }
    }

    f32x16 acc0, acc1;
#pragma unroll
    for (int i = 0; i < 16; ++i) { acc0[i] = 0.f; acc1[i] = 0.f; }

    unsigned held[8];                        // rows 16-31 of current slice, (g0,g1) packed

    // ---- phase-1 slice for r: rows 0-15 -> hTq slots now, rows 16-31 -> held ----
    auto phase1 = [&](int r) {
        f16x8 w1f0 = *(const f16x8*)(w1p + ((r * 2 + 0) * 64 + lane) * 8);
        f16x8 w1f1 = *(const f16x8*)(w1p + ((r * 2 + 1) * 64 + lane) * 8);
#pragma unroll
        for (int g = 0; g < 2; ++g) {
            f32x16 h;
#pragma unroll
            for (int i = 0; i < 16; ++i) h[i] = 0.f;
            h = __builtin_amdgcn_mfma_f32_32x32x16_f16(w1f0, eaf[g][0].v, h, 0, 0, 0);
            h = __builtin_amdgcn_mfma_f32_32x32x16_f16(w1f1, eaf[g][1].v, h, 0, 0, 0);
#pragma unroll
            for (int i = 0; i < 16; ++i) {
                int row = (i & 3) + ((i >> 2) << 3) + (half << 2);   // verified C/D map
                float hv = fmaxf(h[i] + b1[r * 32 + row], 0.f);
                unsigned short us = __half_as_ushort(__float2half(hv));
                if (i < 8) {
                    hTq[w][row][l][g] = us;                  // rows 0-15: slot == row
                } else {
                    int j = i - 8;                           // rows 16-31: hold in regs
                    if (g == 0) held[j] = us;
                    else        held[j] |= (unsigned)us << 16;
                }
            }
        }
    };

    // writes held rows into slots (wave-private; between chunk q=3 and q=4)
    auto flushHeld = [&]() {
#pragma unroll
        for (int j = 0; j < 8; ++j) {
            int slot = (j & 3) + ((j >> 2) << 3) + (half << 2);   // row-16
            *(unsigned*)&hTq[w][slot][l][0] = held[j];
        }
    };

    // compute one 4-c chunk from RB
    auto compute = [&](int cc, const _Float16* RB) {
#pragma unroll
        for (int cl = 0; cl < 4; ++cl) {
            unsigned u = *(const unsigned*)&hTq[w][((cc & 3) << 2) + cl][l][0];
            __half2 hp = *reinterpret_cast<const __half2*>(&u);
            __half2 h0 = __half2half2(__low2half(hp));       // dup for group 0
            __half2 h1 = __half2half2(__high2half(hp));      // dup for group 1
#pragma unroll
            for (int ih = 0; ih < 2; ++ih) {
                f16x8 bfr = *(const f16x8*)(RB + (((cl << 1) + ih) * 64 + lane) * 8);
                u8h A;
#pragma unroll
                for (int p = 0; p < 4; ++p)
                    A.h2[p] = __hmul2(h0, xs0[ih * 4 + p]);      // v_pk_mul_f16
                acc0 = __builtin_amdgcn_mfma_f32_32x32x16_f16(A.v, bfr, acc0, 0, 0, 0);
#pragma unroll
                for (int p = 0; p < 4; ++p)
                    A.h2[p] = __hmul2(h1, xs1[ih * 4 + p]);
                acc1 = __builtin_amdgcn_mfma_f32_32x32x16_f16(A.v, bfr, acc1, 0, 0, 0);
            }
        }
    };

    // ---- pipeline: c0/c1 already in flight; then 1 barrier per chunk ----
    phase1(0);
    __syncthreads();                       // drains both prologue loads

#pragma unroll 1
    for (int r = 0; r < 4; ++r) {
        if (r > 0) phase1(r);              // wave-private hTq: no barrier needed
#pragma unroll
        for (int q = 0; q < 8; ++q) {
            const int cc = r * 8 + q;
            if (q == 4) flushHeld();       // rows 16-31 into the 16 slots
            compute(cc, w2c[q & 1]);
            __syncthreads();               // all waves done reading buf (q&1)
            if (cc + 2 < 32) issueChunk(cc + 2, q & 1);   // async refill; drains
        }                                  // at the barrier one chunk later
    }

    // ---- b2 contribution: extra K-step with h == 1 (A-fragment = xs, no VALU) ----
#pragma unroll
    for (int ih = 0; ih < 2; ++ih) {
        f16x8 bfr = *(const f16x8*)(b2p + (ih * 64 + lane) * 8);
        u8h A;
#pragma unroll
        for (int p = 0; p < 4; ++p) A.h2[p] = xs0[ih * 4 + p];
        acc0 = __builtin_amdgcn_mfma_f32_32x32x16_f16(A.v, bfr, acc0, 0, 0, 0);
#pragma unroll
        for (int p = 0; p < 4; ++p) A.h2[p] = xs1[ih * 4 + p];
        acc1 = __builtin_amdgcn_mfma_f32_32x32x16_f16(A.v, bfr, acc1, 0, 0, 0);
    }

    // ---- scatter into this block's replica (skip for clamped tail waves) ----
    if (live) {
#pragma unroll
        for (int i = 0; i < 16; ++i) {
            int el = (i & 3) + ((i >> 2) << 3) + (half << 2);
            atomicAdd(myout + ei[EE + ebw +      el] * 32 + l, acc0[i]);
            atomicAdd(myout + ei[EE + ebw + 32 + el] * 32 + l, acc1[i]);
        }
    }
}

extern "C" void kernel_launch(void* const* d_in, const int* in_sizes, int n_in,
                              void* d_out, int out_size, void* d_ws, size_t ws_size,
                              hipStream_t stream) {
    const float* x    = (const float*)d_in[0];
    const int*   ei   = (const int*)  d_in[1];
    const float* ea   = (const float*)d_in[2];
    const float* w1   = (const float*)d_in[3];
    const float* b1   = (const float*)d_in[4];
    const float* w2   = (const float*)d_in[5];
    const float* b2   = (const float*)d_in[6];
    const float* root = (const float*)d_in[7];
    const float* bias = (const float*)d_in[8];
    float* out = (float*)d_out;

    _Float16* w2p = (_Float16*)d_ws;                      // 262144 B
    _Float16* w1p = (_Float16*)((char*)d_ws + 262144);    //   8192 B
    _Float16* b2p = (_Float16*)((char*)d_ws + 270336);    //   2048 B
    const size_t partOff = 272384;
    const size_t one = 800000ull * sizeof(float);         // 3.2 MB per replica
    size_t avail = (ws_size > partOff) ? ws_size - partOff : 0;
    int nc = 0;
    for (int c = 8; c >= 1; c >>= 1)
        if ((size_t)c * one <= avail) { nc = c; break; }

    float* part = (float*)((char*)d_ws + partOff);
    if (nc > 0) {
        int nzero4 = nc * 200000;                         // float4 count
        int zb = (nzero4 + 255) / 256;
        prep_kernel<<<532 + zb, 256, 0, stream>>>(w1, w2, b2, w2p, w1p, b2p,
                                                  (float4*)part, nzero4);
        edge_kernel<<<(EE + 255) / 256, 256, 0, stream>>>(x, ei, ea, b1, w2p, w1p, b2p,
                                                          part, nc - 1);
        final_kernel<<<(NN * 32) / 256, 256, 0, stream>>>(x, root, bias, part, nc, out);
    } else {
        prep_kernel<<<532, 256, 0, stream>>>(w1, w2, b2, w2p, w1p, b2p, (float4*)part, 0);
        final_kernel<<<(NN * 32) / 256, 256, 0, stream>>>(x, root, bias, part, 0, out);
        edge_kernel<<<(EE + 255) / 256, 256, 0, stream>>>(x, ei, ea, b1, w2p, w1p, b2p,
                                                          out, 0);
    }
}